// Round 3
// baseline (839.029 us; speedup 1.0000x reference)
//
#include <hip/hip_runtime.h>
#include <cstdint>

#define N_ANCH 8400
#define WMAX   132          // ceil(8400/64)
#define NB     (WMAX * 64)  // padded box slots: 8448
#define NT     512          // k_scan threads (8 waves)
#define M_MAX  17           // col-word groups per wave: words q+8m cover 0..135

__device__ __forceinline__ uint64_t readlane64(uint64_t v, int lane) {
  unsigned lo = (unsigned)__builtin_amdgcn_readlane((int)(unsigned)(v & 0xffffffffull), lane);
  unsigned hi = (unsigned)__builtin_amdgcn_readlane((int)(unsigned)(v >> 32), lane);
  return ((uint64_t)hi << 32) | lo;
}

// Kernel A: exact stable rank (descending score, invalid -> -inf, ties by index),
// scatter boxes/scores into sorted order, count valid. (unchanged, verified)
__global__ __launch_bounds__(256) void k_rank(const float* __restrict__ in,
                                              float* __restrict__ scores_s,
                                              float4* __restrict__ boxes_s,
                                              unsigned* __restrict__ nvp) {
  __shared__ alignas(16) float sc[N_ANCH];
  __shared__ int part[256];
  const int tid = threadIdx.x;
  const float* srow = in + 4 * N_ANCH;
  for (int j = tid; j < N_ANCH; j += 256) sc[j] = srow[j];
  __syncthreads();
  const int il = tid & 63, q = tid >> 6;
  const int i = blockIdx.x * 64 + il;
  const float si = (i < N_ANCH) ? sc[i] : 0.0f;
  const bool valid = si > 0.5f;
  const float key = valid ? si : -INFINITY;
  int cnt = 0;
  const float4* sc4 = (const float4*)sc;
  const int jb = q * (N_ANCH / 4);
  for (int jj = 0; jj < (N_ANCH / 16); ++jj) {
    float4 v = sc4[q * (N_ANCH / 16) + jj];
    int j0 = jb + jj * 4;
    float k0 = (v.x > 0.5f) ? v.x : -INFINITY;
    float k1 = (v.y > 0.5f) ? v.y : -INFINITY;
    float k2 = (v.z > 0.5f) ? v.z : -INFINITY;
    float k3 = (v.w > 0.5f) ? v.w : -INFINITY;
    cnt += (k0 > key) || (k0 == key && (j0 + 0) < i);
    cnt += (k1 > key) || (k1 == key && (j0 + 1) < i);
    cnt += (k2 > key) || (k2 == key && (j0 + 2) < i);
    cnt += (k3 > key) || (k3 == key && (j0 + 3) < i);
  }
  part[tid] = cnt;
  __syncthreads();
  if (q == 0 && i < N_ANCH) {
    int r = part[il] + part[64 + il] + part[128 + il] + part[192 + il];
    float cx = in[0 * N_ANCH + i], cy = in[1 * N_ANCH + i];
    float w  = in[2 * N_ANCH + i], h  = in[3 * N_ANCH + i];
    float x1 = cx - w * 0.5f, y1 = cy - h * 0.5f;
    float x2 = cx + w * 0.5f, y2 = cy + h * 0.5f;
    boxes_s[r] = make_float4(x1, y1, x2, y2);
    scores_s[r] = valid ? si : 0.0f;
    if (valid) atomicAdd(nvp, 1u);
  }
}

// Kernel B: ONLY the diagonal 64x64 suppression blocks (exact verified IoU path).
// diag[b*64 + r] bit l = IoU(box_{64b+r}, box_{64b+l}) > 0.5, masked to l < nv-64b.
__global__ __launch_bounds__(64) void k_diag(const float4* __restrict__ boxes_s,
                                             const unsigned* __restrict__ nvp,
                                             unsigned long long* __restrict__ diag) {
  const int b = blockIdx.x;
  const int lane = threadIdx.x;
  const int nv = (int)*nvp;
  __shared__ float bx1[64], by1[64], bx2[64], by2[64], bar[64];
  float4 bb = boxes_s[b * 64 + lane];
  bx1[lane] = bb.x; by1[lane] = bb.y; bx2[lane] = bb.z; by2[lane] = bb.w;
  float ai = (bb.z - bb.x) * (bb.w - bb.y);
  bar[lane] = ai;
  __syncthreads();
  const int jmax = nv - b * 64;
  uint64_t bits = 0;
  #pragma unroll 8
  for (int l = 0; l < 64; ++l) {
    float lx = fmaxf(bb.x, bx1[l]);
    float ly = fmaxf(bb.y, by1[l]);
    float rx = fminf(bb.z, bx2[l]);
    float ry = fminf(bb.w, by2[l]);
    float dx = fmaxf(rx - lx, 0.0f);
    float dy = fmaxf(ry - ly, 0.0f);
    float inter = dx * dy;
    asm volatile("" : "+v"(inter));           // block fma-contraction into union
    float uni = (ai + bar[l]) - inter;        // reference op order
    float iou = inter / uni;                  // IEEE f32 div
    bits |= ((uint64_t)((l < jmax) && (iou > 0.5f))) << l;
  }
  diag[b * 64 + lane] = bits;
}

// Kernel C: single-workgroup scan; diagonal resolve from prefetched diag words,
// apply phase recomputes suppression on the fly against register-resident columns.
__global__ __launch_bounds__(NT) void k_scan(const float* __restrict__ scores_s,
                                             const float4* __restrict__ boxes_s,
                                             const unsigned long long* __restrict__ diag_g,
                                             const unsigned* __restrict__ nvp,
                                             float* __restrict__ out) {
  __shared__ uint64_t keep_s[WMAX];
  __shared__ float bbx1[64], bby1[64], bbx2[64], bby2[64], bbar[64];
  const int tid = threadIdx.x;
  const int lane = tid & 63;
  const int q = tid >> 6;                      // wave id 0..7
  const int nv = (int)*nvp;
  const int W  = (nv + 63) >> 6;

  for (int idx = tid; idx < WMAX; idx += NT) {
    uint64_t v = 0; int base = idx * 64;
    if (base < nv) { int rem = nv - base; v = (rem >= 64) ? ~0ull : ((1ull << rem) - 1ull); }
    keep_s[idx] = v;
  }

  // Column registers: thread owns col 64*(q+8m)+lane for m = 0..M_MAX-1.
  float cx1[M_MAX], cy1[M_MAX], cx2[M_MAX], cy2[M_MAX], car[M_MAX];
  #pragma unroll
  for (int m = 0; m < M_MAX; ++m) {
    cx1[m] = 0.f; cy1[m] = 0.f; cx2[m] = 0.f; cy2[m] = 0.f; car[m] = 0.f;
    int wd = q + 8 * m;
    if (wd < W) {
      float4 b = boxes_s[(size_t)wd * 64 + lane];
      cx1[m] = b.x; cy1[m] = b.y; cx2[m] = b.z; cy2[m] = b.w;
      car[m] = (b.z - b.x) * (b.w - b.y);
    }
  }

  // One-block-ahead prefetch state.
  uint64_t dw = 0; float4 nb = make_float4(0.f, 0.f, 0.f, 0.f);
  if (q == 0 && W > 0) dw = (uint64_t)diag_g[lane];
  if (q == 1 && W > 0) nb = boxes_s[lane];

  asm volatile("s_waitcnt lgkmcnt(0)" ::: "memory");
  __builtin_amdgcn_sched_barrier(0);
  __builtin_amdgcn_s_barrier();
  __builtin_amdgcn_sched_barrier(0);

  for (int k = 0; k < W; ++k) {
    // --- part A: wave0 resolves diag block k; wave1 stages block k's row boxes ---
    if (q == 1) {
      float4 b = nb;
      if (k + 1 < W) nb = boxes_s[(size_t)(k + 1) * 64 + lane];
      bbx1[lane] = b.x; bby1[lane] = b.y; bbx2[lane] = b.z; bby2[lane] = b.w;
      bbar[lane] = (b.z - b.x) * (b.w - b.y);
    }
    if (q == 0) {
      uint64_t cur = dw;
      if (k + 1 < W) dw = (uint64_t)diag_g[(size_t)(k + 1) * 64 + lane];
      uint64_t bk = keep_s[k];
      uint64_t cand = bk;
      while (cand) {
        int r = (int)__builtin_ctzll(cand);
        uint64_t sr = readlane64(cur, r);
        uint64_t m = sr & ~((2ull << r) - 1ull);   // cols strictly > r
        cand &= ~(1ull << r);
        cand &= ~m;
        bk   &= ~m;
      }
      if (lane == 0) keep_s[k] = bk;
    }
    asm volatile("s_waitcnt lgkmcnt(0)" ::: "memory");
    __builtin_amdgcn_sched_barrier(0);
    __builtin_amdgcn_s_barrier();
    __builtin_amdgcn_sched_barrier(0);

    // --- part B: all waves apply kept rows of block k to later cols (on-the-fly IoU) ---
    uint64_t bk2 = keep_s[k];
    if (bk2) {
      uint32_t supm = 0;
      uint64_t rem = bk2;
      while (rem) {
        int r = (int)__builtin_ctzll(rem);
        rem &= rem - 1;
        float rx1 = bbx1[r], ry1 = bby1[r], rx2 = bbx2[r], ry2 = bby2[r], rar = bbar[r];
        #pragma unroll
        for (int m = 0; m < M_MAX; ++m) {
          int wd = q + 8 * m;
          if (wd > k && wd < W) {
            float lx = fmaxf(rx1, cx1[m]);
            float ly = fmaxf(ry1, cy1[m]);
            float hx = fminf(rx2, cx2[m]);
            float hy = fminf(ry2, cy2[m]);
            float dx = fmaxf(hx - lx, 0.0f);
            float dy = fmaxf(hy - ly, 0.0f);
            float I = dx * dy;
            asm volatile("" : "+v"(I));        // forbid fma into union
            float u1 = rar + car[m];
            float U  = u1 - I;                 // reference union rounding
            float diff = __builtin_fmaf(2.0f, I, -U);   // RN(2I - U), exact product
            float t = U * 0x1p-24f;            // exact scale
            // RN(I/U) > 0.5  <=>  2I-U > U*2^-24 ; only diff==t is ambiguous.
            bool sup = diff > t;
            if (diff == t) sup = (I / U) > 0.5f;   // exact rare path (also handles U==0)
            supm |= ((uint32_t)sup) << m;
          }
        }
      }
      #pragma unroll
      for (int m = 0; m < M_MAX; ++m) {
        int wd = q + 8 * m;
        if (wd > k && wd < W) {
          uint64_t bal = __ballot((supm >> m) & 1u);
          if (lane == 0) keep_s[wd] &= ~bal;
        }
      }
    }
    asm volatile("s_waitcnt lgkmcnt(0)" ::: "memory");
    __builtin_amdgcn_sched_barrier(0);
    __builtin_amdgcn_s_barrier();
    __builtin_amdgcn_sched_barrier(0);
  }

  // --- emit output ---
  for (int r = tid; r < N_ANCH; r += NT) {
    bool kept = (r < nv) && ((keep_s[r >> 6] >> (r & 63)) & 1ull);
    float4 b = kept ? boxes_s[r] : make_float4(0.f, 0.f, 0.f, 0.f);
    float s = kept ? scores_s[r] : 0.0f;
    out[r * 5 + 0] = b.x;
    out[r * 5 + 1] = b.y;
    out[r * 5 + 2] = b.z;
    out[r * 5 + 3] = b.w;
    out[r * 5 + 4] = s;
  }
}

extern "C" void kernel_launch(void* const* d_in, const int* in_sizes, int n_in,
                              void* d_out, int out_size, void* d_ws, size_t ws_size,
                              hipStream_t stream) {
  const float* in = (const float*)d_in[0];
  float* out = (float*)d_out;
  uint8_t* ws = (uint8_t*)d_ws;
  unsigned* nvp = (unsigned*)ws;                                   // 64 B
  float* scores_s = (float*)(ws + 64);                             // 33600 B
  float4* boxes_s = (float4*)(ws + 64 + 33600);                    // NB*16 = 135168 B
  unsigned long long* diag = (unsigned long long*)(ws + 64 + 33600 + (size_t)NB * 16);  // 67584 B

  hipMemsetAsync(ws, 0, 64, stream);
  k_rank<<<dim3(WMAX), dim3(256), 0, stream>>>(in, scores_s, boxes_s, nvp);
  k_diag<<<dim3(WMAX), dim3(64), 0, stream>>>(boxes_s, nvp, diag);
  k_scan<<<dim3(1), dim3(NT), 0, stream>>>(scores_s, boxes_s, diag, nvp, out);
}

// Round 4
// 258.024 us; speedup vs baseline: 3.2517x; 3.2517x over previous
//
#include <hip/hip_runtime.h>
#include <cstdint>

#define N_ANCH 8400
#define WMAX   132          // ceil(8400/64)
#define NB     (WMAX * 64)  // padded box slots: 8448
#define NT     128          // k_scan threads (2 waves)

__device__ __forceinline__ uint64_t readlane64(uint64_t v, int lane) {
  unsigned lo = (unsigned)__builtin_amdgcn_readlane((int)(unsigned)(v & 0xffffffffull), lane);
  unsigned hi = (unsigned)__builtin_amdgcn_readlane((int)(unsigned)(v >> 32), lane);
  return ((uint64_t)hi << 32) | lo;
}

// Kernel A: exact stable rank (descending score, invalid -> -inf, ties by index),
// scatter boxes/scores into sorted order, count valid. (unchanged, verified)
__global__ __launch_bounds__(256) void k_rank(const float* __restrict__ in,
                                              float* __restrict__ scores_s,
                                              float4* __restrict__ boxes_s,
                                              unsigned* __restrict__ nvp) {
  __shared__ alignas(16) float sc[N_ANCH];
  __shared__ int part[256];
  const int tid = threadIdx.x;
  const float* srow = in + 4 * N_ANCH;
  for (int j = tid; j < N_ANCH; j += 256) sc[j] = srow[j];
  __syncthreads();
  const int il = tid & 63, q = tid >> 6;
  const int i = blockIdx.x * 64 + il;
  const float si = (i < N_ANCH) ? sc[i] : 0.0f;
  const bool valid = si > 0.5f;
  const float key = valid ? si : -INFINITY;
  int cnt = 0;
  const float4* sc4 = (const float4*)sc;
  const int jb = q * (N_ANCH / 4);
  for (int jj = 0; jj < (N_ANCH / 16); ++jj) {
    float4 v = sc4[q * (N_ANCH / 16) + jj];
    int j0 = jb + jj * 4;
    float k0 = (v.x > 0.5f) ? v.x : -INFINITY;
    float k1 = (v.y > 0.5f) ? v.y : -INFINITY;
    float k2 = (v.z > 0.5f) ? v.z : -INFINITY;
    float k3 = (v.w > 0.5f) ? v.w : -INFINITY;
    cnt += (k0 > key) || (k0 == key && (j0 + 0) < i);
    cnt += (k1 > key) || (k1 == key && (j0 + 1) < i);
    cnt += (k2 > key) || (k2 == key && (j0 + 2) < i);
    cnt += (k3 > key) || (k3 == key && (j0 + 3) < i);
  }
  part[tid] = cnt;
  __syncthreads();
  if (q == 0 && i < N_ANCH) {
    int r = part[il] + part[64 + il] + part[128 + il] + part[192 + il];
    float cx = in[0 * N_ANCH + i], cy = in[1 * N_ANCH + i];
    float w  = in[2 * N_ANCH + i], h  = in[3 * N_ANCH + i];
    float x1 = cx - w * 0.5f, y1 = cy - h * 0.5f;
    float x2 = cx + w * 0.5f, y2 = cy + h * 0.5f;
    boxes_s[r] = make_float4(x1, y1, x2, y2);
    scores_s[r] = valid ? si : 0.0f;
    if (valid) atomicAdd(nvp, 1u);
  }
}

// Kernel B: full suppression matrix, ROW-major sup[i*W + w] (contiguous row
// slices for the scan), plus contiguous diag[] (diag[i] = word of i's own block).
// Exact verified IoU float path.
__global__ __launch_bounds__(256) void k_sup(const float4* __restrict__ boxes_s,
                                             const unsigned* __restrict__ nvp,
                                             unsigned long long* __restrict__ sup,
                                             unsigned long long* __restrict__ diag) {
  const int nv = (int)*nvp;
  const int W = (nv + 63) >> 6;
  const int w = blockIdx.x;
  if (w >= W) return;
  __shared__ float bx1[64], by1[64], bx2[64], by2[64], bar[64];
  const int tid = threadIdx.x;
  if (tid < 64) {
    int j = w * 64 + tid;
    float4 b = (j < N_ANCH) ? boxes_s[j] : make_float4(0.f, 0.f, 0.f, 0.f);
    bx1[tid] = b.x; by1[tid] = b.y; bx2[tid] = b.z; by2[tid] = b.w;
    bar[tid] = (b.z - b.x) * (b.w - b.y);
  }
  __syncthreads();
  const int i = blockIdx.y * 256 + tid;
  if (i >= nv) return;
  float4 bi = boxes_s[i];
  float ai = (bi.z - bi.x) * (bi.w - bi.y);
  const int jmax = nv - w * 64;
  uint64_t bits = 0;
  #pragma unroll 8
  for (int l = 0; l < 64; ++l) {
    float lx = fmaxf(bi.x, bx1[l]);
    float ly = fmaxf(bi.y, by1[l]);
    float rx = fminf(bi.z, bx2[l]);
    float ry = fminf(bi.w, by2[l]);
    float dx = fmaxf(rx - lx, 0.0f);
    float dy = fmaxf(ry - ly, 0.0f);
    float inter = dx * dy;
    asm volatile("" : "+v"(inter));           // block fma-contraction into union
    float uni = (ai + bar[l]) - inter;        // reference op order
    float iou = inter / uni;                  // IEEE f32 div, matches numpy
    bits |= ((uint64_t)((l < jmax) && (iou > 0.5f))) << l;
  }
  sup[(size_t)i * W + w] = bits;
  if (w == (i >> 6)) diag[i] = bits;
}

// Kernel C: single-workgroup scan. Diag resolve from prefetched diag words;
// apply fetches only KEPT rows' contiguous word-slices, 8 rows batched per
// round trip (clamped-index loads, no divergence, coalesced across lanes).
__global__ __launch_bounds__(NT) void k_scan(const float* __restrict__ scores_s,
                                             const float4* __restrict__ boxes_s,
                                             const unsigned long long* __restrict__ sup_,
                                             const unsigned long long* __restrict__ diag_g,
                                             const unsigned* __restrict__ nvp,
                                             float* __restrict__ out) {
  __shared__ uint64_t keep_s[WMAX];
  const uint64_t* sup = (const uint64_t*)sup_;
  const int tid = threadIdx.x;
  const int lane = tid & 63;
  const int q = tid >> 6;
  const int nv = (int)*nvp;
  const int W  = (nv + 63) >> 6;

  for (int idx = tid; idx < WMAX; idx += NT) {
    uint64_t v = 0; int base = idx * 64;
    if (base < nv) { int rem = nv - base; v = (rem >= 64) ? ~0ull : ((1ull << rem) - 1ull); }
    keep_s[idx] = v;
  }

  uint64_t dw = 0;
  if (q == 0 && W > 0) dw = (uint64_t)diag_g[lane];
  __syncthreads();

  for (int k = 0; k < W; ++k) {
    // --- diagonal resolve (wave0): serial ctz-skip chain over surviving rows ---
    if (q == 0) {
      uint64_t cur = dw;
      if (k + 1 < W) dw = (uint64_t)diag_g[(size_t)(k + 1) * 64 + lane];
      uint64_t bk = keep_s[k];
      uint64_t cand = bk;
      while (cand) {
        int r = (int)__builtin_ctzll(cand);
        uint64_t sr = readlane64(cur, r);
        uint64_t m = sr & ~((2ull << r) - 1ull);   // cols strictly > r
        cand &= ~(1ull << r);
        cand &= ~m;
        bk   &= ~m;
      }
      if (lane == 0) keep_s[k] = bk;
    }
    __syncthreads();

    // --- apply: OR kept rows' slice words into keep (8 rows per round trip) ---
    const uint64_t bk2 = keep_s[k];
    if (bk2) {
      const int rowbase = k * 64;
      for (int wd = k + 1 + tid; wd < W; wd += NT) {
        uint64_t acc = 0;
        uint64_t rem = bk2;
        while (rem) {
          int r0, r1, r2, r3, r4, r5, r6, r7;
          uint64_t m0, m1, m2, m3, m4, m5, m6, m7;
          r0 = (int)__builtin_ctzll(rem); rem &= rem - 1;
          m1 = (uint64_t)0 - (uint64_t)(rem != 0);
          r1 = rem ? (int)__builtin_ctzll(rem) : r0; rem &= rem - 1;
          m2 = (uint64_t)0 - (uint64_t)(rem != 0);
          r2 = rem ? (int)__builtin_ctzll(rem) : r0; rem &= rem - 1;
          m3 = (uint64_t)0 - (uint64_t)(rem != 0);
          r3 = rem ? (int)__builtin_ctzll(rem) : r0; rem &= rem - 1;
          m4 = (uint64_t)0 - (uint64_t)(rem != 0);
          r4 = rem ? (int)__builtin_ctzll(rem) : r0; rem &= rem - 1;
          m5 = (uint64_t)0 - (uint64_t)(rem != 0);
          r5 = rem ? (int)__builtin_ctzll(rem) : r0; rem &= rem - 1;
          m6 = (uint64_t)0 - (uint64_t)(rem != 0);
          r6 = rem ? (int)__builtin_ctzll(rem) : r0; rem &= rem - 1;
          m7 = (uint64_t)0 - (uint64_t)(rem != 0);
          r7 = rem ? (int)__builtin_ctzll(rem) : r0; rem &= rem - 1;
          // 8 independent coalesced loads -> one vmcnt wait
          uint64_t v0 = sup[(size_t)(rowbase + r0) * W + wd];
          uint64_t v1 = sup[(size_t)(rowbase + r1) * W + wd];
          uint64_t v2 = sup[(size_t)(rowbase + r2) * W + wd];
          uint64_t v3 = sup[(size_t)(rowbase + r3) * W + wd];
          uint64_t v4 = sup[(size_t)(rowbase + r4) * W + wd];
          uint64_t v5 = sup[(size_t)(rowbase + r5) * W + wd];
          uint64_t v6 = sup[(size_t)(rowbase + r6) * W + wd];
          uint64_t v7 = sup[(size_t)(rowbase + r7) * W + wd];
          acc |= v0 | (v1 & m1) | (v2 & m2) | (v3 & m3)
                    | (v4 & m4) | (v5 & m5) | (v6 & m6) | (v7 & m7);
        }
        keep_s[wd] &= ~acc;
      }
    }
    __syncthreads();
  }

  // --- emit output ---
  for (int r = tid; r < N_ANCH; r += NT) {
    bool kept = (r < nv) && ((keep_s[r >> 6] >> (r & 63)) & 1ull);
    float4 b = kept ? boxes_s[r] : make_float4(0.f, 0.f, 0.f, 0.f);
    float s = kept ? scores_s[r] : 0.0f;
    out[r * 5 + 0] = b.x;
    out[r * 5 + 1] = b.y;
    out[r * 5 + 2] = b.z;
    out[r * 5 + 3] = b.w;
    out[r * 5 + 4] = s;
  }
}

extern "C" void kernel_launch(void* const* d_in, const int* in_sizes, int n_in,
                              void* d_out, int out_size, void* d_ws, size_t ws_size,
                              hipStream_t stream) {
  const float* in = (const float*)d_in[0];
  float* out = (float*)d_out;
  uint8_t* ws = (uint8_t*)d_ws;
  unsigned* nvp = (unsigned*)ws;                                       // 64 B
  float* scores_s = (float*)(ws + 64);                                 // 33600 B
  float4* boxes_s = (float4*)(ws + 64 + 33600);                        // NB*16 = 135168 B
  unsigned long long* diag = (unsigned long long*)(ws + 64 + 33600 + (size_t)NB * 16);   // NB*8
  unsigned long long* sup  = (unsigned long long*)(ws + 64 + 33600 + (size_t)NB * 24);   // ~2.23 MB

  hipMemsetAsync(ws, 0, 64, stream);
  k_rank<<<dim3(WMAX), dim3(256), 0, stream>>>(in, scores_s, boxes_s, nvp);
  k_sup<<<dim3(WMAX, (N_ANCH + 255) / 256), dim3(256), 0, stream>>>(boxes_s, nvp, sup, diag);
  k_scan<<<dim3(1), dim3(NT), 0, stream>>>(scores_s, boxes_s, sup, diag, nvp, out);
}